// Round 1
// 554.318 us; speedup vs baseline: 1.2619x; 1.2619x over previous
//
#include <hip/hip_runtime.h>
#include <hip/hip_bf16.h>

#define NODES 100000
#define EDGES 1600000
#define FEAT 512
#define HID 128
#define NCLS 40
#define NPAD 48                      // NCLS padded to 3 MFMA n-tiles

// ---- bucketed CSR build params ----
#define NPB 128                         // nodes per bucket (dst >> 7)
#define NB_BKT ((NODES + NPB - 1) / NPB)  // 782 buckets
#define CHUNK 8192                      // edges per workgroup in binning
#define NWG_BIN ((EDGES + CHUNK - 1) / CHUNK)  // 196

typedef __bf16 bf16x8 __attribute__((ext_vector_type(8)));
typedef float f32x4 __attribute__((ext_vector_type(4)));

static __device__ inline __bf16 cvt_bf16(float f) {
  union { __hip_bfloat16 h; __bf16 b; } u;
  u.h = __float2bfloat16(f);
  return u.b;
}

static __device__ inline __hip_bfloat162 pack_bf162(float a, float b) {
  __hip_bfloat162 r;
  r.x = __float2bfloat16(a);
  r.y = __float2bfloat16(b);
  return r;
}

// ---------------- CSR build, bucketed ----------------
// k1: per-wg LDS histogram over dst buckets -> global bucket counts
__global__ __launch_bounds__(256) void bin_count(const int* __restrict__ ei,
                                                 int* __restrict__ bcnt) {
  __shared__ int h[NB_BKT];
  int tid = threadIdx.x;
  for (int i = tid; i < NB_BKT; i += 256) h[i] = 0;
  __syncthreads();
  int base = blockIdx.x * CHUNK;
#pragma unroll
  for (int rep = 0; rep < CHUNK / 1024; rep++) {
    int e = base + rep * 1024 + (tid << 2);
    if (e < EDGES) {  // EDGES % 4 == 0, so full int4 is in-bounds
      int4 d = *(const int4*)(ei + EDGES + e);
      atomicAdd(&h[d.x >> 7], 1);
      atomicAdd(&h[d.y >> 7], 1);
      atomicAdd(&h[d.z >> 7], 1);
      atomicAdd(&h[d.w >> 7], 1);
    }
  }
  __syncthreads();
  for (int i = tid; i < NB_BKT; i += 256)
    if (h[i]) atomicAdd(&bcnt[i], h[i]);
}

// k2: single-block exclusive scan of bucket counts -> bucket bases + cursors
__global__ __launch_bounds__(1024) void bucket_scan(const int* __restrict__ bcnt,
                                                    int* __restrict__ bbase,
                                                    int* __restrict__ bcur) {
  __shared__ int tmp[1024];
  int i = threadIdx.x;
  int v = (i < NB_BKT) ? bcnt[i] : 0;
  tmp[i] = v;
  __syncthreads();
#pragma unroll
  for (int off = 1; off < 1024; off <<= 1) {
    int t = 0;
    if (i >= off) t = tmp[i - off];
    __syncthreads();
    if (i >= off) tmp[i] += t;
    __syncthreads();
  }
  if (i < NB_BKT) {
    int ex = tmp[i] - v;
    bbase[i] = ex;
    bcur[i] = ex;
  }
}

// k3: per-wg histogram + bucket range reservation, packed scatter into
// bucket-contiguous staging. payload = (src<<7) | (dst & 127)
__global__ __launch_bounds__(256) void bin_scatter(const int* __restrict__ ei,
                                                   int* __restrict__ bcur,
                                                   unsigned int* __restrict__ staged) {
  __shared__ int h[NB_BKT];
  int tid = threadIdx.x;
  for (int i = tid; i < NB_BKT; i += 256) h[i] = 0;
  __syncthreads();
  int base = blockIdx.x * CHUNK;
  // pass A: count this chunk
#pragma unroll
  for (int rep = 0; rep < CHUNK / 1024; rep++) {
    int e = base + rep * 1024 + (tid << 2);
    if (e < EDGES) {
      int4 d = *(const int4*)(ei + EDGES + e);
      atomicAdd(&h[d.x >> 7], 1);
      atomicAdd(&h[d.y >> 7], 1);
      atomicAdd(&h[d.z >> 7], 1);
      atomicAdd(&h[d.w >> 7], 1);
    }
  }
  __syncthreads();
  // reserve ranges; convert h[] into running write cursors
  for (int i = tid; i < NB_BKT; i += 256) {
    int c = h[i];
    h[i] = c ? atomicAdd(&bcur[i], c) : 0;
  }
  __syncthreads();
  // pass B: scatter packed payloads into reserved runs
#pragma unroll
  for (int rep = 0; rep < CHUNK / 1024; rep++) {
    int e = base + rep * 1024 + (tid << 2);
    if (e < EDGES) {
      int4 s = *(const int4*)(ei + e);
      int4 d = *(const int4*)(ei + EDGES + e);
      int p0 = atomicAdd(&h[d.x >> 7], 1);
      staged[p0] = ((unsigned)s.x << 7) | ((unsigned)d.x & 127u);
      int p1 = atomicAdd(&h[d.y >> 7], 1);
      staged[p1] = ((unsigned)s.y << 7) | ((unsigned)d.y & 127u);
      int p2 = atomicAdd(&h[d.z >> 7], 1);
      staged[p2] = ((unsigned)s.z << 7) | ((unsigned)d.z & 127u);
      int p3 = atomicAdd(&h[d.w >> 7], 1);
      staged[p3] = ((unsigned)s.w << 7) | ((unsigned)d.w & 127u);
    }
  }
}

// k4: one wg per bucket: per-node histogram + scan (-> deg, dinv, row_start),
// then node-grouped scatter into adj (writes confined to bucket's adj region)
__global__ __launch_bounds__(256) void build_bucket(const unsigned int* __restrict__ staged,
                                                    const int* __restrict__ bbase,
                                                    const int* __restrict__ bcnt,
                                                    int* __restrict__ deg,
                                                    float* __restrict__ dinv,
                                                    int* __restrict__ row_start,
                                                    int* __restrict__ adj) {
  __shared__ int hist[NPB];
  __shared__ int sc[NPB];
  __shared__ int cur[NPB];
  int tid = threadIdx.x;
  int b = blockIdx.x;
  int n0 = b * NPB;
  int s = bbase[b];
  int cnt = bcnt[b];
  if (tid < NPB) hist[tid] = 0;
  __syncthreads();
  for (int i = tid; i < cnt; i += 256) {
    unsigned int v = staged[s + i];
    atomicAdd(&hist[v & 127u], 1);
  }
  __syncthreads();
  if (tid < NPB) sc[tid] = hist[tid];
  __syncthreads();
#pragma unroll
  for (int off = 1; off < NPB; off <<= 1) {
    int t = 0;
    if (tid < NPB && tid >= off) t = sc[tid - off];
    __syncthreads();
    if (tid < NPB && tid >= off) sc[tid] += t;
    __syncthreads();
  }
  if (tid < NPB) {
    int node = n0 + tid;
    int rs = s + sc[tid] - hist[tid];
    cur[tid] = rs;
    if (node < NODES) {
      row_start[node] = rs;
      deg[node] = hist[tid];
      dinv[node] = rsqrtf((float)hist[tid] + 1.0f);  // +1 = self loop
    }
  }
  __syncthreads();
  for (int i = tid; i < cnt; i += 256) {
    unsigned int v = staged[s + i];
    int pos = atomicAdd(&cur[v & 127u], 1);
    adj[pos] = (int)(v >> 7);
  }
}

// ---------------- weight transposes (f32 -> bf16) ----------------
__global__ void tr_w1(const float* __restrict__ w1, __hip_bfloat16* __restrict__ w1t) {
  int idx = blockIdx.x * blockDim.x + threadIdx.x;  // over FEAT*HID
  if (idx >= FEAT * HID) return;
  int k = idx / HID, n = idx % HID;
  w1t[n * FEAT + k] = __float2bfloat16(w1[idx]);
}

__global__ void tr_w2(const float* __restrict__ w2, __hip_bfloat16* __restrict__ w2t) {
  int idx = blockIdx.x * blockDim.x + threadIdx.x;  // over NPAD*HID
  if (idx >= NPAD * HID) return;
  int n = idx / HID, k = idx % HID;
  w2t[n * HID + k] = (n < NCLS) ? __float2bfloat16(w2[k * NCLS + n]) : __float2bfloat16(0.0f);
}

// ---------------- GEMM1: 128x128 LDS-tiled, coalesced staging ----------------
__global__ __launch_bounds__(256) void gemm1_kernel(const float* __restrict__ x,
                                                    const __hip_bfloat16* __restrict__ w1t,
                                                    __hip_bfloat16* __restrict__ h0) {
  __shared__ __hip_bfloat16 Asw[128 * 128];  // 32 KB: [row][16B-chunk ^ (row&15)]
  __shared__ bf16x8 Bfrag[2048];             // 32 KB: [(n*4+ks)*64 + lane]
  int tid = threadIdx.x;
  int wave = tid >> 6, lane = tid & 63;
  int r = lane & 15, quad = lane >> 4;
  int m_base = blockIdx.x * 128;

  f32x4 acc[2][8];
#pragma unroll
  for (int mt = 0; mt < 2; mt++)
#pragma unroll
    for (int n = 0; n < 8; n++) acc[mt][n] = (f32x4){0.f, 0.f, 0.f, 0.f};

  for (int kc = 0; kc < FEAT; kc += 128) {
    __syncthreads();
#pragma unroll
    for (int rep = 0; rep < 8; rep++) {
      int f = tid + rep * 256;
      int row = f >> 4, cc = f & 15;
      int grow = m_base + row;
      f32x4 a0 = (f32x4){0.f, 0.f, 0.f, 0.f}, a1 = a0;
      if (grow < NODES) {
        const float* src = x + (size_t)grow * FEAT + kc + cc * 8;
        a0 = *(const f32x4*)src;
        a1 = *(const f32x4*)(src + 4);
      }
      bf16x8 bb;
      bb[0] = cvt_bf16(a0[0]); bb[1] = cvt_bf16(a0[1]);
      bb[2] = cvt_bf16(a0[2]); bb[3] = cvt_bf16(a0[3]);
      bb[4] = cvt_bf16(a1[0]); bb[5] = cvt_bf16(a1[1]);
      bb[6] = cvt_bf16(a1[2]); bb[7] = cvt_bf16(a1[3]);
      *(bf16x8*)(Asw + row * 128 + ((cc ^ (row & 15)) * 8)) = bb;
    }
#pragma unroll
    for (int rep = 0; rep < 8; rep++) {
      int f = tid + rep * 256;
      int fl = f & 63, ks = (f >> 6) & 3, n = f >> 8;
      int fr = fl & 15, fq = fl >> 4;
      Bfrag[f] = *(const bf16x8*)(w1t + (size_t)(n * 16 + fr) * FEAT + kc + ks * 32 + fq * 8);
    }
    __syncthreads();
#pragma unroll
    for (int ks = 0; ks < 4; ks++) {
      bf16x8 bf[8];
#pragma unroll
      for (int n = 0; n < 8; n++) bf[n] = Bfrag[(n * 4 + ks) * 64 + lane];
#pragma unroll
      for (int mt = 0; mt < 2; mt++) {
        int row = (wave * 2 + mt) * 16 + r;
        bf16x8 af = *(bf16x8*)(Asw + row * 128 + (((ks * 4 + quad) ^ r) * 8));
#pragma unroll
        for (int n = 0; n < 8; n++)
          acc[mt][n] = __builtin_amdgcn_mfma_f32_16x16x32_bf16(af, bf[n], acc[mt][n], 0, 0, 0);
      }
    }
  }
#pragma unroll
  for (int mt = 0; mt < 2; mt++) {
    int mrow = m_base + (wave * 2 + mt) * 16 + quad * 4;
#pragma unroll
    for (int n = 0; n < 8; n++)
#pragma unroll
      for (int rr = 0; rr < 4; rr++) {
        int row = mrow + rr;
        if (row < NODES) h0[(size_t)row * HID + n * 16 + r] = __float2bfloat16(acc[mt][n][rr]);
      }
  }
}

// ---------------- fused agg1 + epilogue1: h = relu(sum_nbrs + self + b1) ----------------
__global__ __launch_bounds__(256) void agg1_fused(
    const int* __restrict__ row_start, const int* __restrict__ deg,
    const int* __restrict__ adj, const float* __restrict__ dinv,
    const float* __restrict__ b1, const __hip_bfloat16* __restrict__ h0,
    __hip_bfloat16* __restrict__ h) {
  int wave = threadIdx.x >> 6, lane = threadIdx.x & 63;
  int node = blockIdx.x * 4 + wave;
  if (node >= NODES) return;
  float di = dinv[node];
  float2 f = __bfloat1622float2(((const __hip_bfloat162*)(h0 + (size_t)node * HID))[lane]);
  float ax = f.x * di * di, ay = f.y * di * di;  // self loop
  int start = row_start[node], end = start + deg[node];
  int p = start;
  for (; p + 8 <= end; p += 8) {
    int s[8];
    float nr[8];
    float2 v[8];
#pragma unroll
    for (int j = 0; j < 8; j++) s[j] = adj[p + j];
#pragma unroll
    for (int j = 0; j < 8; j++) nr[j] = dinv[s[j]] * di;
#pragma unroll
    for (int j = 0; j < 8; j++)
      v[j] = __bfloat1622float2(((const __hip_bfloat162*)(h0 + (size_t)s[j] * HID))[lane]);
#pragma unroll
    for (int j = 0; j < 8; j++) { ax += v[j].x * nr[j]; ay += v[j].y * nr[j]; }
  }
  for (; p < end; ++p) {
    int s = adj[p];
    float nrm = dinv[s] * di;
    float2 v = __bfloat1622float2(((const __hip_bfloat162*)(h0 + (size_t)s * HID))[lane]);
    ax += v.x * nrm;
    ay += v.y * nrm;
  }
  float2 b = ((const float2*)b1)[lane];
  ax = fmaxf(ax + b.x, 0.0f);
  ay = fmaxf(ay + b.y, 0.0f);
  ((__hip_bfloat162*)(h + (size_t)node * HID))[lane] = pack_bf162(ax, ay);
}

// ---------------- GEMM2: h1[N,40] = h[N,128] @ W2 ----------------
__global__ __launch_bounds__(256) void gemm2_kernel(const __hip_bfloat16* __restrict__ h,
                                                    const __hip_bfloat16* __restrict__ w2t,
                                                    float* __restrict__ h1) {
  int wave = threadIdx.x >> 6;
  int lane = threadIdx.x & 63;
  int m0 = (blockIdx.x * 4 + wave) * 16;
  if (m0 >= NODES) return;
  int r = lane & 15, quad = lane >> 4;
  const bf16x8* arow = (const bf16x8*)(h + (size_t)(m0 + r) * HID + quad * 8);
  f32x4 acc[3];
#pragma unroll
  for (int n = 0; n < 3; n++) acc[n] = (f32x4){0.f, 0.f, 0.f, 0.f};
#pragma unroll
  for (int k0 = 0; k0 < HID; k0 += 32) {
    bf16x8 a = arow[k0 / 8];
#pragma unroll
    for (int n = 0; n < 3; n++) {
      const bf16x8* brow = (const bf16x8*)(w2t + (size_t)(n * 16 + r) * HID + k0 + quad * 8);
      acc[n] = __builtin_amdgcn_mfma_f32_16x16x32_bf16(a, *brow, acc[n], 0, 0, 0);
    }
  }
#pragma unroll
  for (int n = 0; n < 3; n++)
#pragma unroll
    for (int rr = 0; rr < 4; rr++) {
      int col = n * 16 + r;
      if (col < NCLS) h1[(size_t)(m0 + quad * 4 + rr) * NCLS + col] = acc[n][rr];
    }
}

// ---------------- fused agg2 + bias + self loop + log_softmax ----------------
__global__ __launch_bounds__(256) void agg2_fused(
    const int* __restrict__ row_start, const int* __restrict__ deg,
    const int* __restrict__ adj, const float* __restrict__ dinv,
    const float* __restrict__ b2, const float* __restrict__ h1,
    float* __restrict__ out) {
  int wave = threadIdx.x >> 6, lane = threadIdx.x & 63;
  int node = blockIdx.x * 4 + wave;
  if (node >= NODES) return;
  float di = dinv[node];
  bool act = lane < NCLS;
  float acc = act ? h1[(size_t)node * NCLS + lane] * di * di : 0.0f;  // self loop
  int start = row_start[node], end = start + deg[node];
  int p = start;
  for (; p + 8 <= end; p += 8) {
    int s[8];
    float nr[8];
#pragma unroll
    for (int j = 0; j < 8; j++) s[j] = adj[p + j];
#pragma unroll
    for (int j = 0; j < 8; j++) nr[j] = dinv[s[j]] * di;
    if (act) {
      float v[8];
#pragma unroll
      for (int j = 0; j < 8; j++) v[j] = h1[(size_t)s[j] * NCLS + lane];
#pragma unroll
      for (int j = 0; j < 8; j++) acc += v[j] * nr[j];
    }
  }
  for (; p < end; ++p) {
    int s = adj[p];
    float nrm = dinv[s] * di;
    if (act) acc += h1[(size_t)s * NCLS + lane] * nrm;
  }
  float v = act ? acc + b2[lane] : -1e30f;
  float m = v;
#pragma unroll
  for (int o = 32; o > 0; o >>= 1) m = fmaxf(m, __shfl_xor(m, o));
  float ex = act ? expf(v - m) : 0.0f;
  float ssum = ex;
#pragma unroll
  for (int o = 32; o > 0; o >>= 1) ssum += __shfl_xor(ssum, o);
  if (act) out[(size_t)node * NCLS + lane] = v - m - logf(ssum);
}

extern "C" void kernel_launch(void* const* d_in, const int* in_sizes, int n_in,
                              void* d_out, int out_size, void* d_ws, size_t ws_size,
                              hipStream_t stream) {
  const float* x  = (const float*)d_in[0];
  const int* ei   = (const int*)d_in[1];
  const float* W1 = (const float*)d_in[2];
  const float* b1 = (const float*)d_in[3];
  const float* W2 = (const float*)d_in[4];
  const float* b2 = (const float*)d_in[5];
  float* out = (float*)d_out;

  char* ws = (char*)d_ws;
  int* deg_i          = (int*)(ws + 0);                    // 400 KB
  float* dinv         = (float*)(ws + (size_t)512 * 1024); // 400 KB
  int* row_start      = (int*)(ws + (size_t)1024 * 1024);  // 400 KB
  int* bcnt           = (int*)(ws + (size_t)1536 * 1024);  // ~3.1 KB
  int* bbase          = (int*)(ws + (size_t)1544 * 1024);  // ~3.1 KB
  int* bcur           = (int*)(ws + (size_t)1552 * 1024);  // ~3.1 KB
  int* adj            = (int*)(ws + (size_t)2560 * 1024);  // 6.4 MB -> ends ~8.9 MB
  __hip_bfloat16* w1t = (__hip_bfloat16*)(ws + (size_t)9728 * 1024);   // 128 KB
  __hip_bfloat16* w2t = (__hip_bfloat16*)(ws + (size_t)9856 * 1024);   // 12 KB
  __hip_bfloat16* h0  = (__hip_bfloat16*)(ws + (size_t)10 * 1048576);  // 25.6 MB -> ends 35.6
  __hip_bfloat16* h   = (__hip_bfloat16*)(ws + (size_t)36 * 1048576);  // 25.6 MB -> ends 61.6
  float* h1           = (float*)(ws + (size_t)10 * 1048576);           // alias h0 (dead after agg1_fused)
  // staged packed edges (6.4 MB): aliases h0 region — dead before gemm1 writes h0
  unsigned int* staged = (unsigned int*)(ws + (size_t)10 * 1048576);

  (void)hipMemsetAsync(bcnt, 0, (size_t)NB_BKT * 4, stream);

  bin_count<<<NWG_BIN, 256, 0, stream>>>(ei, bcnt);
  bucket_scan<<<1, 1024, 0, stream>>>(bcnt, bbase, bcur);
  bin_scatter<<<NWG_BIN, 256, 0, stream>>>(ei, bcur, staged);
  build_bucket<<<NB_BKT, 256, 0, stream>>>(staged, bbase, bcnt, deg_i, dinv, row_start, adj);

  tr_w1<<<(FEAT * HID + 255) / 256, 256, 0, stream>>>(W1, w1t);
  tr_w2<<<(NPAD * HID + 255) / 256, 256, 0, stream>>>(W2, w2t);

  gemm1_kernel<<<(NODES + 127) / 128, 256, 0, stream>>>(x, w1t, h0);
  agg1_fused<<<(NODES + 3) / 4, 256, 0, stream>>>(row_start, deg_i, adj, dinv, b1, h0, h);
  gemm2_kernel<<<(NODES / 16 + 3) / 4, 256, 0, stream>>>(h, w2t, h1);
  agg2_fused<<<(NODES + 3) / 4, 256, 0, stream>>>(row_start, deg_i, adj, dinv, b2, h1, out);
}

// Round 2
// 549.723 us; speedup vs baseline: 1.2724x; 1.0084x over previous
//
#include <hip/hip_runtime.h>
#include <hip/hip_bf16.h>

#define NODES 100000
#define EDGES 1600000
#define FEAT 512
#define HID 128
#define NCLS 40
#define NPAD 48                      // NCLS padded to 3 MFMA n-tiles

// ---- bucketed CSR build params ----
#define NPB 128                          // nodes per bucket (dst >> 7)
#define NB_BKT ((NODES + NPB - 1) / NPB) // 782 buckets
#define CAP 4096                         // slots per bucket (expected 2048, sigma 45)
#define CHUNK 4096                       // edges per workgroup in binning
#define NWG_BIN ((EDGES + CHUNK - 1) / CHUNK)  // 391

typedef __bf16 bf16x8 __attribute__((ext_vector_type(8)));
typedef float f32x4 __attribute__((ext_vector_type(4)));

static __device__ inline __bf16 cvt_bf16(float f) {
  union { __hip_bfloat16 h; __bf16 b; } u;
  u.h = __float2bfloat16(f);
  return u.b;
}

static __device__ inline __hip_bfloat162 pack_bf162(float a, float b) {
  __hip_bfloat162 r;
  r.x = __float2bfloat16(a);
  r.y = __float2bfloat16(b);
  return r;
}

// ---------------- CSR build, bucketed, fixed-capacity ----------------
// k1: per-wg LDS histogram + bucket range reservation, packed scatter into
// bucket-strided staging at b*CAP. payload = (src<<7) | (dst & 127)
__global__ __launch_bounds__(256) void bin_scatter(const int* __restrict__ ei,
                                                   int* __restrict__ bcur,
                                                   unsigned int* __restrict__ staged) {
  __shared__ int h[NB_BKT];
  int tid = threadIdx.x;
  for (int i = tid; i < NB_BKT; i += 256) h[i] = 0;
  __syncthreads();
  int base = blockIdx.x * CHUNK;
  // pass A: count this chunk
#pragma unroll
  for (int rep = 0; rep < CHUNK / 1024; rep++) {
    int e = base + rep * 1024 + (tid << 2);
    if (e < EDGES) {  // EDGES % 4 == 0, so full int4 is in-bounds
      int4 d = *(const int4*)(ei + EDGES + e);
      atomicAdd(&h[d.x >> 7], 1);
      atomicAdd(&h[d.y >> 7], 1);
      atomicAdd(&h[d.z >> 7], 1);
      atomicAdd(&h[d.w >> 7], 1);
    }
  }
  __syncthreads();
  // reserve within-bucket ranges; convert h[] into running write cursors
  for (int i = tid; i < NB_BKT; i += 256) {
    int c = h[i];
    h[i] = c ? atomicAdd(&bcur[i], c) : 0;
  }
  __syncthreads();
  // pass B: scatter packed payloads into reserved runs
#pragma unroll
  for (int rep = 0; rep < CHUNK / 1024; rep++) {
    int e = base + rep * 1024 + (tid << 2);
    if (e < EDGES) {
      int4 s = *(const int4*)(ei + e);
      int4 d = *(const int4*)(ei + EDGES + e);
      int b0 = d.x >> 7;
      int p0 = atomicAdd(&h[b0], 1);
      staged[b0 * CAP + p0] = ((unsigned)s.x << 7) | ((unsigned)d.x & 127u);
      int b1 = d.y >> 7;
      int p1 = atomicAdd(&h[b1], 1);
      staged[b1 * CAP + p1] = ((unsigned)s.y << 7) | ((unsigned)d.y & 127u);
      int b2 = d.z >> 7;
      int p2 = atomicAdd(&h[b2], 1);
      staged[b2 * CAP + p2] = ((unsigned)s.z << 7) | ((unsigned)d.z & 127u);
      int b3 = d.w >> 7;
      int p3 = atomicAdd(&h[b3], 1);
      staged[b3 * CAP + p3] = ((unsigned)s.w << 7) | ((unsigned)d.w & 127u);
    }
  }
}

// k2: one wg per bucket: per-node histogram + padded scan (-> deg, dinv,
// row_start 16B-aligned), node-grouped scatter into bucket-strided adj
__global__ __launch_bounds__(256) void build_bucket(const unsigned int* __restrict__ staged,
                                                    const int* __restrict__ bcur,
                                                    int* __restrict__ deg,
                                                    float* __restrict__ dinv,
                                                    int* __restrict__ row_start,
                                                    int* __restrict__ adj) {
  __shared__ int hist[NPB];
  __shared__ int sc[NPB];
  __shared__ int cur[NPB];
  int tid = threadIdx.x;
  int b = blockIdx.x;
  int n0 = b * NPB;
  int s = b * CAP;
  int cnt = bcur[b];
  if (tid < NPB) hist[tid] = 0;
  __syncthreads();
  for (int i = tid; i < cnt; i += 256) {
    unsigned int v = staged[s + i];
    atomicAdd(&hist[v & 127u], 1);
  }
  __syncthreads();
  int pad = 0;
  if (tid < NPB) {
    pad = (hist[tid] + 3) & ~3;  // 16B-aligned rows for int4 adj loads
    sc[tid] = pad;
  }
  __syncthreads();
#pragma unroll
  for (int off = 1; off < NPB; off <<= 1) {
    int t = 0;
    if (tid < NPB && tid >= off) t = sc[tid - off];
    __syncthreads();
    if (tid < NPB && tid >= off) sc[tid] += t;
    __syncthreads();
  }
  if (tid < NPB) {
    int node = n0 + tid;
    int rs = s + sc[tid] - pad;   // sum of pads <= cnt + 3*128 < CAP
    cur[tid] = rs;
    if (node < NODES) {
      row_start[node] = rs;
      deg[node] = hist[tid];
      dinv[node] = rsqrtf((float)hist[tid] + 1.0f);  // +1 = self loop
    }
  }
  __syncthreads();
  for (int i = tid; i < cnt; i += 256) {
    unsigned int v = staged[s + i];
    int pos = atomicAdd(&cur[v & 127u], 1);
    adj[pos] = (int)(v >> 7);
  }
}

// ---------------- weight transposes (f32 -> bf16), merged ----------------
__global__ void tr_w(const float* __restrict__ w1, const float* __restrict__ w2,
                     __hip_bfloat16* __restrict__ w1t, __hip_bfloat16* __restrict__ w2t) {
  int idx = blockIdx.x * blockDim.x + threadIdx.x;
  if (idx < FEAT * HID) {
    int k = idx / HID, n = idx % HID;
    w1t[n * FEAT + k] = __float2bfloat16(w1[idx]);
  } else {
    int j = idx - FEAT * HID;
    if (j < NPAD * HID) {
      int n = j / HID, k = j % HID;
      w2t[n * HID + k] = (n < NCLS) ? __float2bfloat16(w2[k * NCLS + n]) : __float2bfloat16(0.0f);
    }
  }
}

// ---------------- GEMM1: 128x128 LDS-tiled; epilogue scales by dinv[row] ----------------
__global__ __launch_bounds__(256) void gemm1_kernel(const float* __restrict__ x,
                                                    const __hip_bfloat16* __restrict__ w1t,
                                                    const float* __restrict__ dinv,
                                                    __hip_bfloat16* __restrict__ h0s) {
  __shared__ __hip_bfloat16 Asw[128 * 128];  // 32 KB: [row][16B-chunk ^ (row&15)]
  __shared__ bf16x8 Bfrag[2048];             // 32 KB: [(n*4+ks)*64 + lane]
  int tid = threadIdx.x;
  int wave = tid >> 6, lane = tid & 63;
  int r = lane & 15, quad = lane >> 4;
  int m_base = blockIdx.x * 128;

  f32x4 acc[2][8];
#pragma unroll
  for (int mt = 0; mt < 2; mt++)
#pragma unroll
    for (int n = 0; n < 8; n++) acc[mt][n] = (f32x4){0.f, 0.f, 0.f, 0.f};

  for (int kc = 0; kc < FEAT; kc += 128) {
    __syncthreads();
#pragma unroll
    for (int rep = 0; rep < 8; rep++) {
      int f = tid + rep * 256;
      int row = f >> 4, cc = f & 15;
      int grow = m_base + row;
      f32x4 a0 = (f32x4){0.f, 0.f, 0.f, 0.f}, a1 = a0;
      if (grow < NODES) {
        const float* src = x + (size_t)grow * FEAT + kc + cc * 8;
        a0 = *(const f32x4*)src;
        a1 = *(const f32x4*)(src + 4);
      }
      bf16x8 bb;
      bb[0] = cvt_bf16(a0[0]); bb[1] = cvt_bf16(a0[1]);
      bb[2] = cvt_bf16(a0[2]); bb[3] = cvt_bf16(a0[3]);
      bb[4] = cvt_bf16(a1[0]); bb[5] = cvt_bf16(a1[1]);
      bb[6] = cvt_bf16(a1[2]); bb[7] = cvt_bf16(a1[3]);
      *(bf16x8*)(Asw + row * 128 + ((cc ^ (row & 15)) * 8)) = bb;
    }
#pragma unroll
    for (int rep = 0; rep < 8; rep++) {
      int f = tid + rep * 256;
      int fl = f & 63, ks = (f >> 6) & 3, n = f >> 8;
      int fr = fl & 15, fq = fl >> 4;
      Bfrag[f] = *(const bf16x8*)(w1t + (size_t)(n * 16 + fr) * FEAT + kc + ks * 32 + fq * 8);
    }
    __syncthreads();
#pragma unroll
    for (int ks = 0; ks < 4; ks++) {
      bf16x8 bf[8];
#pragma unroll
      for (int n = 0; n < 8; n++) bf[n] = Bfrag[(n * 4 + ks) * 64 + lane];
#pragma unroll
      for (int mt = 0; mt < 2; mt++) {
        int row = (wave * 2 + mt) * 16 + r;
        bf16x8 af = *(bf16x8*)(Asw + row * 128 + (((ks * 4 + quad) ^ r) * 8));
#pragma unroll
        for (int n = 0; n < 8; n++)
          acc[mt][n] = __builtin_amdgcn_mfma_f32_16x16x32_bf16(af, bf[n], acc[mt][n], 0, 0, 0);
      }
    }
  }
#pragma unroll
  for (int mt = 0; mt < 2; mt++) {
    int mrow = m_base + (wave * 2 + mt) * 16 + quad * 4;
    f32x4 dv = *(const f32x4*)(dinv + mrow);  // mrow % 4 == 0; OOB rows read ws garbage, unused
#pragma unroll
    for (int n = 0; n < 8; n++)
#pragma unroll
      for (int rr = 0; rr < 4; rr++) {
        int row = mrow + rr;
        if (row < NODES)
          h0s[(size_t)row * HID + n * 16 + r] = __float2bfloat16(acc[mt][n][rr] * dv[rr]);
      }
  }
}

// ---------------- fused agg1 + epilogue1: h = relu(di * sum(h0s) + b1) ----------------
// h0s rows are pre-scaled by dinv[src]; per-edge dinv gathers eliminated.
__global__ __launch_bounds__(256) void agg1_fused(
    const int* __restrict__ row_start, const int* __restrict__ deg,
    const int* __restrict__ adj, const float* __restrict__ dinv,
    const float* __restrict__ b1, const __hip_bfloat16* __restrict__ h0s,
    __hip_bfloat16* __restrict__ h) {
  int wave = threadIdx.x >> 6, lane = threadIdx.x & 63;
  int node = blockIdx.x * 4 + wave;
  if (node >= NODES) return;
  float di = dinv[node];
  float2 f = __bfloat1622float2(((const __hip_bfloat162*)(h0s + (size_t)node * HID))[lane]);
  float ax = f.x, ay = f.y;  // self loop: h0s[node] already carries dinv[node]
  int start = row_start[node], end = start + deg[node];
  int p = start;
  for (; p + 8 <= end; p += 8) {  // row_start is 16B-aligned
    int4 a0 = *(const int4*)(adj + p);
    int4 a1 = *(const int4*)(adj + p + 4);
    int s[8] = {a0.x, a0.y, a0.z, a0.w, a1.x, a1.y, a1.z, a1.w};
    float2 v[8];
#pragma unroll
    for (int j = 0; j < 8; j++)
      v[j] = __bfloat1622float2(((const __hip_bfloat162*)(h0s + (size_t)s[j] * HID))[lane]);
#pragma unroll
    for (int j = 0; j < 8; j++) { ax += v[j].x; ay += v[j].y; }
  }
  for (; p < end; ++p) {
    int s = adj[p];
    float2 v = __bfloat1622float2(((const __hip_bfloat162*)(h0s + (size_t)s * HID))[lane]);
    ax += v.x;
    ay += v.y;
  }
  float2 b = ((const float2*)b1)[lane];
  ax = fmaxf(ax * di + b.x, 0.0f);
  ay = fmaxf(ay * di + b.y, 0.0f);
  ((__hip_bfloat162*)(h + (size_t)node * HID))[lane] = pack_bf162(ax, ay);
}

// ---------------- GEMM2: h1s[N,40] = (h[N,128] @ W2) * dinv[row] ----------------
__global__ __launch_bounds__(256) void gemm2_kernel(const __hip_bfloat16* __restrict__ h,
                                                    const __hip_bfloat16* __restrict__ w2t,
                                                    const float* __restrict__ dinv,
                                                    float* __restrict__ h1s) {
  int wave = threadIdx.x >> 6;
  int lane = threadIdx.x & 63;
  int m0 = (blockIdx.x * 4 + wave) * 16;
  if (m0 >= NODES) return;
  int r = lane & 15, quad = lane >> 4;
  const bf16x8* arow = (const bf16x8*)(h + (size_t)(m0 + r) * HID + quad * 8);
  f32x4 acc[3];
#pragma unroll
  for (int n = 0; n < 3; n++) acc[n] = (f32x4){0.f, 0.f, 0.f, 0.f};
#pragma unroll
  for (int k0 = 0; k0 < HID; k0 += 32) {
    bf16x8 a = arow[k0 / 8];
#pragma unroll
    for (int n = 0; n < 3; n++) {
      const bf16x8* brow = (const bf16x8*)(w2t + (size_t)(n * 16 + r) * HID + k0 + quad * 8);
      acc[n] = __builtin_amdgcn_mfma_f32_16x16x32_bf16(a, *brow, acc[n], 0, 0, 0);
    }
  }
  f32x4 dv = *(const f32x4*)(dinv + m0 + quad * 4);
#pragma unroll
  for (int n = 0; n < 3; n++)
#pragma unroll
    for (int rr = 0; rr < 4; rr++) {
      int col = n * 16 + r;
      if (col < NCLS)
        h1s[(size_t)(m0 + quad * 4 + rr) * NCLS + col] = acc[n][rr] * dv[rr];
    }
}

// ---------------- fused agg2 + bias + self loop + log_softmax ----------------
__global__ __launch_bounds__(256) void agg2_fused(
    const int* __restrict__ row_start, const int* __restrict__ deg,
    const int* __restrict__ adj, const float* __restrict__ dinv,
    const float* __restrict__ b2, const float* __restrict__ h1s,
    float* __restrict__ out) {
  int wave = threadIdx.x >> 6, lane = threadIdx.x & 63;
  int node = blockIdx.x * 4 + wave;
  if (node >= NODES) return;
  float di = dinv[node];
  bool act = lane < NCLS;
  float acc = act ? h1s[(size_t)node * NCLS + lane] : 0.0f;  // self loop pre-scaled
  int start = row_start[node], end = start + deg[node];
  int p = start;
  for (; p + 8 <= end; p += 8) {
    int4 a0 = *(const int4*)(adj + p);
    int4 a1 = *(const int4*)(adj + p + 4);
    int s[8] = {a0.x, a0.y, a0.z, a0.w, a1.x, a1.y, a1.z, a1.w};
    if (act) {
      float v[8];
#pragma unroll
      for (int j = 0; j < 8; j++) v[j] = h1s[(size_t)s[j] * NCLS + lane];
#pragma unroll
      for (int j = 0; j < 8; j++) acc += v[j];
    }
  }
  for (; p < end; ++p) {
    int s = adj[p];
    if (act) acc += h1s[(size_t)s * NCLS + lane];
  }
  float v = act ? acc * di + b2[lane] : -1e30f;
  float m = v;
#pragma unroll
  for (int o = 32; o > 0; o >>= 1) m = fmaxf(m, __shfl_xor(m, o));
  float ex = act ? expf(v - m) : 0.0f;
  float ssum = ex;
#pragma unroll
  for (int o = 32; o > 0; o >>= 1) ssum += __shfl_xor(ssum, o);
  if (act) out[(size_t)node * NCLS + lane] = v - m - logf(ssum);
}

extern "C" void kernel_launch(void* const* d_in, const int* in_sizes, int n_in,
                              void* d_out, int out_size, void* d_ws, size_t ws_size,
                              hipStream_t stream) {
  const float* x  = (const float*)d_in[0];
  const int* ei   = (const int*)d_in[1];
  const float* W1 = (const float*)d_in[2];
  const float* b1 = (const float*)d_in[3];
  const float* W2 = (const float*)d_in[4];
  const float* b2 = (const float*)d_in[5];
  float* out = (float*)d_out;

  char* ws = (char*)d_ws;
  int* deg_i          = (int*)(ws + 0);                    // 400 KB
  float* dinv         = (float*)(ws + (size_t)512 * 1024); // 400 KB
  int* row_start      = (int*)(ws + (size_t)1024 * 1024);  // 400 KB
  int* bcur           = (int*)(ws + (size_t)1536 * 1024);  // ~3.1 KB
  int* adj            = (int*)(ws + (size_t)2 * 1048576);  // 12.8 MB -> ends ~14.8 MB
  __hip_bfloat16* w1t = (__hip_bfloat16*)(ws + (size_t)15 * 1048576);  // 128 KB
  __hip_bfloat16* w2t = (__hip_bfloat16*)(ws + (size_t)15 * 1048576 + 256 * 1024);  // 12 KB
  // staged (12.8 MB) aliases h0s region: dead before gemm1 writes h0s
  unsigned int* staged = (unsigned int*)(ws + (size_t)16 * 1048576);
  __hip_bfloat16* h0s = (__hip_bfloat16*)(ws + (size_t)16 * 1048576);  // 25.6 MB -> ends 41.6
  __hip_bfloat16* h   = (__hip_bfloat16*)(ws + (size_t)42 * 1048576);  // 25.6 MB -> ends 67.6
  float* h1s          = (float*)(ws + (size_t)16 * 1048576);           // alias h0s (dead after agg1)

  (void)hipMemsetAsync(bcur, 0, (size_t)NB_BKT * 4, stream);

  bin_scatter<<<NWG_BIN, 256, 0, stream>>>(ei, bcur, staged);
  build_bucket<<<NB_BKT, 256, 0, stream>>>(staged, bcur, deg_i, dinv, row_start, adj);

  tr_w<<<(FEAT * HID + NPAD * HID + 255) / 256, 256, 0, stream>>>(W1, W2, w1t, w2t);

  gemm1_kernel<<<(NODES + 127) / 128, 256, 0, stream>>>(x, w1t, dinv, h0s);
  agg1_fused<<<(NODES + 3) / 4, 256, 0, stream>>>(row_start, deg_i, adj, dinv, b1, h0s, h);
  gemm2_kernel<<<(NODES / 16 + 3) / 4, 256, 0, stream>>>(h, w2t, dinv, h1s);
  agg2_fused<<<(NODES + 3) / 4, 256, 0, stream>>>(row_start, deg_i, adj, dinv, b2, h1s, out);
}